// Round 5
// baseline (1902.888 us; speedup 1.0000x reference)
//
#include <hip/hip_runtime.h>
#include <hip/hip_bf16.h>

typedef __attribute__((ext_vector_type(8))) short short8;
typedef __attribute__((ext_vector_type(4))) float f32x4;

#define BB 16
#define VV 3
#define NN 512
#define SS 5
#define TT 32
#define DTDX 0.1f

__device__ __forceinline__ float fast_tanh(float x) {
  float xc = fminf(fmaxf(x, -9.f), 9.f);
  float e = __expf(2.f * xc);
  return (e - 1.f) * __builtin_amdgcn_rcpf(e + 1.f);
}

__device__ __forceinline__ short f2bf(float x) {
  __hip_bfloat16 h = __float2bfloat16(x);
  return __builtin_bit_cast(short, h);
}

// ---------------- init: weight repack ----------------
// W1T[j][c] fp32 [512][16] (c=15 zero-padded)
// W2F: fragment-ordered bf16: frag(ct,ks,lane) at ((ct*16+ks)*64+lane)*8
// W3F: fragment-ordered bf16 for W3 (cols>=5 zero): frag(ks,lane)
__global__ void init_repack(const float* __restrict__ W1,
                            const float* __restrict__ W2,
                            const float* __restrict__ W3,
                            float* __restrict__ W1T,
                            short* __restrict__ W2F,
                            short* __restrict__ W3F) {
  const int blk = blockIdx.x;
  const int tid = threadIdx.x;
  if (blk < 128) {
    const int fid = blk * 256 + tid;
    const int lane = fid & 63;
    const int rest = fid >> 6;
    const int ks = rest & 15;
    const int ct = rest >> 4;
    const int col = ct * 16 + (lane & 15);
    const int k0 = ks * 32 + (lane >> 4) * 8;
    short8 v;
#pragma unroll
    for (int q = 0; q < 8; ++q) v[q] = f2bf(W2[(size_t)(k0 + q) * 512 + col]);
    *(short8*)(W2F + (size_t)fid * 8) = v;
  } else if (blk < 132) {
    const int fid = (blk - 128) * 256 + tid;
    const int lane = fid & 63;
    const int ks = fid >> 6;
    const int ml = lane & 15;
    const int k0 = ks * 32 + (lane >> 4) * 8;
    short8 v;
#pragma unroll
    for (int q = 0; q < 8; ++q)
      v[q] = f2bf((ml < 5) ? W3[(size_t)(k0 + q) * 5 + ml] : 0.f);
    *(short8*)(W3F + (size_t)fid * 8) = v;
  } else {
    for (int idx = tid; idx < 512 * 16; idx += 256) {
      const int j = idx >> 4, c = idx & 15;
      W1T[idx] = (c < 15) ? W1[c * 512 + j] : 0.f;
    }
  }
}

// ---------------- persistent all-steps kernel ----------------
// 256 blocks (1/CU), 1024 threads (16 waves). Block = (b, 32-row chunk).
// u lives in LDS across steps; flux halo (5 floats per v) exchanged via
// relaxed agent-scope atomics + neighbor flag spin (parity double-buffered).
// PLAIN launch (not cooperative): 256 blocks of 1024 threads are trivially
// co-resident (1/CU); R4 evidence suggests cooperative dispatch defeats L2
// caching of the W2F stream (4.28 GB/dispatch = 512 KB x 8192 block-steps).
__global__ __launch_bounds__(1024, 4) void persist_kernel(
    const float* __restrict__ u0, const float* __restrict__ W1T,
    const float* __restrict__ b1, const short* __restrict__ W2F,
    const float* __restrict__ b2, const short* __restrict__ W3F,
    const float* __restrict__ b3, float* __restrict__ states,
    float* __restrict__ actions, float* __restrict__ rewards,
    int* __restrict__ eflux, int* __restrict__ flags) {
  __shared__ float u_lds[VV][40];     // u at global n = n0-2+i
  __shared__ float flux_lds[VV][32];  // own flux for n0..n0+31
  __shared__ __align__(16) short h_lds[32 * 512];  // bf16, XOR-swizzled
  __shared__ float logits_lds[32][16];

  const int tid = threadIdx.x;
  const int blk = blockIdx.x;
  // XCD-affinity: whole 16-chunk ring of a given b on one XCD (speed only)
  const int xcd = blk & 7;
  const int sl = blk >> 3;
  const int b = 2 * xcd + (sl >> 4);
  const int c = sl & 15;
  const int n0 = c << 5;
  const int self = b * 16 + c;
  const int left = b * 16 + ((c + 15) & 15);
  const int right = b * 16 + ((c + 1) & 15);

  const int lane = tid & 63;
  const int wv = tid >> 6;
  const int ml = lane & 15;
  const int gg = lane >> 4;
  const int aswz = (ml & 7) << 3;

  const short8* B2p = (const short8*)W2F;
  const int ct0 = wv * 2;

  if (tid < 108) {
    const int v = tid / 36;
    const int i = tid - v * 36;
    u_lds[v][i] = u0[(b * VV + v) * NN + ((n0 - 2 + i) & (NN - 1))];
  }
  __syncthreads();

  for (int t = 0; t <= TT; ++t) {
    if (t > 0) {
      // wait for neighbors' step-(t-1) flux
      if (tid == 0) {
        while (__hip_atomic_load(flags + left * 32, __ATOMIC_RELAXED,
                                 __HIP_MEMORY_SCOPE_AGENT) < t) {}
        while (__hip_atomic_load(flags + right * 32, __ATOMIC_RELAXED,
                                 __HIP_MEMORY_SCOPE_AGENT) < t) {}
      }
      __syncthreads();
      // A': u_t = u_{t-1} - 0.1*(flux - roll(flux,1)); write states[t-1]
      if (tid < 108) {
        const int v = tid / 36;
        const int i = tid - v * 36;  // u index, global n = n0-2+i
        const int ep = (t - 1) & 1;
        const int* lE = eflux + ((ep * 256 + left) * VV + v) * 8;
        const int* rE = eflux + ((ep * 256 + right) * VV + v) * 8;
        // F(j) = flux at global n0-3+j, j in [0,36]
        float Fa, Fb;
        if (i < 3)
          Fa = __int_as_float(__hip_atomic_load(lE + 2 + i, __ATOMIC_RELAXED,
                                                __HIP_MEMORY_SCOPE_AGENT));
        else if (i > 34)
          Fa = __int_as_float(__hip_atomic_load(rE + i - 35, __ATOMIC_RELAXED,
                                                __HIP_MEMORY_SCOPE_AGENT));
        else
          Fa = flux_lds[v][i - 3];
        if (i + 1 < 3)
          Fb = __int_as_float(__hip_atomic_load(lE + 3 + i, __ATOMIC_RELAXED,
                                                __HIP_MEMORY_SCOPE_AGENT));
        else if (i + 1 > 34)
          Fb = __int_as_float(__hip_atomic_load(rE + i - 34, __ATOMIC_RELAXED,
                                                __HIP_MEMORY_SCOPE_AGENT));
        else
          Fb = flux_lds[v][i - 2];
        const float un = u_lds[v][i] - DTDX * (Fb - Fa);
        u_lds[v][i] = un;
        if (i >= 2 && i < 34)
          states[(size_t)(t - 1) * BB * VV * NN + (b * VV + v) * NN +
                 (n0 - 2 + i)] = un;
      }
      __syncthreads();
    }
    if (t == TT) break;

    // ---- B1: h1 = tanh(feats @ W1 + b1), fp32 VALU ----
    {
      const int r = lane & 31;   // row, shared by 2 half-waves
      const int jh = lane >> 5;  // which 16-j half
      const int jbase = wv * 32 + jh * 16;
      float f[15];
#pragma unroll
      for (int v = 0; v < VV; ++v)
#pragma unroll
        for (int s = 0; s < SS; ++s) f[v * 5 + s] = u_lds[v][r + s];
      const int swz = (r & 7) << 3;
#pragma unroll
      for (int hf = 0; hf < 2; ++hf) {
        short8 hb;
#pragma unroll
        for (int q = 0; q < 8; ++q) {
          const int j = jbase + hf * 8 + q;
          const float4* wr = (const float4*)(W1T + j * 16);
          const float4 w0 = wr[0], w1 = wr[1], w2 = wr[2], w3 = wr[3];
          float a = b1[j];
          a += w0.x * f[0] + w0.y * f[1] + w0.z * f[2] + w0.w * f[3];
          a += w1.x * f[4] + w1.y * f[5] + w1.z * f[6] + w1.w * f[7];
          a += w2.x * f[8] + w2.y * f[9] + w2.z * f[10] + w2.w * f[11];
          a += w3.x * f[12] + w3.y * f[13] + w3.z * f[14];
          hb[q] = f2bf(fast_tanh(a));
        }
        const int ke = jbase + hf * 8;
        *(short8*)(&h_lds[r * 512 + (ke ^ swz)]) = hb;
      }
    }
    __syncthreads();

    // ---- B2: h2 = tanh(h1 @ W2 + b2), MFMA, both tiles streamed from L2 ----
    f32x4 acc[2][2];
#pragma unroll
    for (int mt = 0; mt < 2; ++mt)
#pragma unroll
      for (int nt = 0; nt < 2; ++nt) acc[mt][nt] = (f32x4){0.f, 0.f, 0.f, 0.f};
#pragma unroll 4
    for (int ks = 0; ks < 16; ++ks) {
      const int k = ks * 32 + gg * 8;
      const short8 a0 = *(const short8*)(&h_lds[ml * 512 + (k ^ aswz)]);
      const short8 a1 = *(const short8*)(&h_lds[(16 + ml) * 512 + (k ^ aswz)]);
      const short8 b0 = B2p[(ct0 * 16 + ks) * 64 + lane];
      const short8 b1v = B2p[((ct0 + 1) * 16 + ks) * 64 + lane];
      acc[0][0] = __builtin_amdgcn_mfma_f32_16x16x32_bf16(a0, b0, acc[0][0], 0, 0, 0);
      acc[1][0] = __builtin_amdgcn_mfma_f32_16x16x32_bf16(a1, b0, acc[1][0], 0, 0, 0);
      acc[0][1] = __builtin_amdgcn_mfma_f32_16x16x32_bf16(a0, b1v, acc[0][1], 0, 0, 0);
      acc[1][1] = __builtin_amdgcn_mfma_f32_16x16x32_bf16(a1, b1v, acc[1][1], 0, 0, 0);
    }
    __syncthreads();  // all waves done reading h1

    // epilogue: h2 -> h_lds (C layout: row=gg*4+r, col=ml)
#pragma unroll
    for (int nt = 0; nt < 2; ++nt) {
      const int col = (ct0 + nt) * 16 + ml;
      const float bias = b2[col];
#pragma unroll
      for (int mt = 0; mt < 2; ++mt) {
#pragma unroll
        for (int r = 0; r < 4; ++r) {
          const int row = mt * 16 + gg * 4 + r;
          h_lds[row * 512 + (col ^ ((row & 7) << 3))] =
              f2bf(fast_tanh(acc[mt][nt][r] + bias));
        }
      }
    }
    __syncthreads();

    // ---- B3: logits = h2 @ W3 (waves 0,1) ----
    if (wv < 2) {
      f32x4 a3 = (f32x4){0.f, 0.f, 0.f, 0.f};
      const short8* B3p = (const short8*)W3F;
#pragma unroll 4
      for (int ks = 0; ks < 16; ++ks) {
        const int k = ks * 32 + gg * 8;
        const short8 a =
            *(const short8*)(&h_lds[(wv * 16 + ml) * 512 + (k ^ aswz)]);
        const short8 bb = B3p[ks * 64 + lane];
        a3 = __builtin_amdgcn_mfma_f32_16x16x32_bf16(a, bb, a3, 0, 0, 0);
      }
#pragma unroll
      for (int r = 0; r < 4; ++r) logits_lds[wv * 16 + gg * 4 + r][ml] = a3[r];
    }
    __syncthreads();

    // ---- B4: softmax, reward, actions, flux (+ halo publish) ----
    if (tid < 32) {
      const int r = tid;
      const int n = n0 + r;
      float lg[5];
#pragma unroll
      for (int s = 0; s < 5; ++s) lg[s] = logits_lds[r][s] + b3[s];
      const float m =
          fmaxf(fmaxf(fmaxf(lg[0], lg[1]), fmaxf(lg[2], lg[3])), lg[4]);
      float e[5], sum = 0.f;
#pragma unroll
      for (int s = 0; s < 5; ++s) {
        e[s] = __expf(lg[s] - m);
        sum += e[s];
      }
      const float inv = 1.f / sum;
      float w[5], rw = 0.f;
#pragma unroll
      for (int s = 0; s < 5; ++s) {
        w[s] = e[s] * inv;
        rw += w[s] * w[s];
      }
      float* ap = actions + (size_t)t * BB * NN * SS + ((size_t)b * NN + n) * SS;
#pragma unroll
      for (int s = 0; s < 5; ++s) ap[s] = w[s];
      rewards[(size_t)t * BB * NN + b * NN + n] = -rw;
      const int p = t & 1;
#pragma unroll
      for (int v = 0; v < VV; ++v) {
        float fx = 0.f;
#pragma unroll
        for (int s = 0; s < 5; ++s) fx += u_lds[v][r + s] * w[s];
        flux_lds[v][r] = fx;
        int* sE = eflux + ((p * 256 + self) * VV + v) * 8;
        if (r < 2)
          __hip_atomic_store(sE + r, __float_as_int(fx), __ATOMIC_RELAXED,
                             __HIP_MEMORY_SCOPE_AGENT);
        if (r >= 29)
          __hip_atomic_store(sE + 2 + (r - 29), __float_as_int(fx),
                             __ATOMIC_RELAXED, __HIP_MEMORY_SCOPE_AGENT);
      }
    }
    __syncthreads();  // drains vmcnt: halo atomics complete before flag
    if (tid == 0)
      __hip_atomic_store(flags + self * 32, t + 1, __ATOMIC_RELAXED,
                         __HIP_MEMORY_SCOPE_AGENT);
  }
}

extern "C" void kernel_launch(void* const* d_in, const int* in_sizes, int n_in,
                              void* d_out, int out_size, void* d_ws,
                              size_t ws_size, hipStream_t stream) {
  const float* u0 = (const float*)d_in[0];
  const float* W1 = (const float*)d_in[1];
  const float* b1 = (const float*)d_in[2];
  const float* W2 = (const float*)d_in[3];
  const float* b2 = (const float*)d_in[4];
  const float* W3 = (const float*)d_in[5];
  const float* b3 = (const float*)d_in[6];

  float* states = (float*)d_out;                         // [32,16,3,512]
  float* actions = states + (size_t)TT * BB * VV * NN;   // [32,16,512,5]
  float* rewards = actions + (size_t)TT * BB * NN * SS;  // [32,16,512]

  char* ws = (char*)d_ws;
  float* W1T = (float*)ws;                     // 32 KB
  short* W2F = (short*)(ws + 32768);           // 512 KB
  short* W3F = (short*)(ws + 32768 + 524288);  // 16 KB
  int* eflux = (int*)(ws + 32768 + 524288 + 16384);          // 48 KB
  int* flags = (int*)(ws + 32768 + 524288 + 16384 + 49152);  // 32 KB

  hipMemsetAsync(flags, 0, 256 * 32 * sizeof(int), stream);
  init_repack<<<dim3(133), dim3(256), 0, stream>>>(W1, W2, W3, W1T, W2F, W3F);

  // Plain launch: 256 blocks x 1024 threads = exactly 1 block/CU, all
  // co-resident; ring handshake needs no runtime cooperative support.
  persist_kernel<<<dim3(256), dim3(1024), 0, stream>>>(
      u0, W1T, b1, W2F, b2, W3F, b3, states, actions, rewards, eflux, flags);
}

// Round 6
// 1522.495 us; speedup vs baseline: 1.2498x; 1.2498x over previous
//
#include <hip/hip_runtime.h>
#include <hip/hip_bf16.h>

typedef __attribute__((ext_vector_type(8))) short short8;
typedef __attribute__((ext_vector_type(4))) float f32x4;

#define BB 16
#define VV 3
#define NN 512
#define SS 5
#define TT 32
#define DTDX 0.1f

// replica unit: W2F (512 KB) + W3F (16 KB), in shorts
#define REP_SHORTS (262144 + 8192)
#define REP_BYTES (REP_SHORTS * 2)
#define WS_FIXED (32768 + 49152 + 32768)  // W1T + eflux + flags

__device__ __forceinline__ float fast_tanh(float x) {
  float xc = fminf(fmaxf(x, -9.f), 9.f);
  float e = __expf(2.f * xc);
  return (e - 1.f) * __builtin_amdgcn_rcpf(e + 1.f);
}

__device__ __forceinline__ short f2bf(float x) {
  __hip_bfloat16 h = __float2bfloat16(x);
  return __builtin_bit_cast(short, h);
}

// ---------------- init: weight repack (replicated) ----------------
// W1T[j][c] fp32 [512][16] (c=15 zero-padded)
// Each replica r (r < nrep): W2F frag(ct,ks,lane) at WR + r*REP_SHORTS +
// ((ct*16+ks)*64+lane)*8 ; W3F frag(ks,lane) at +262144.
__global__ void init_repack(const float* __restrict__ W1,
                            const float* __restrict__ W2,
                            const float* __restrict__ W3,
                            float* __restrict__ W1T,
                            short* __restrict__ WR, int nrep) {
  const int blk = blockIdx.x;
  const int tid = threadIdx.x;
  if (blk < 128) {
    const int fid = blk * 256 + tid;
    const int lane = fid & 63;
    const int rest = fid >> 6;
    const int ks = rest & 15;
    const int ct = rest >> 4;
    const int col = ct * 16 + (lane & 15);
    const int k0 = ks * 32 + (lane >> 4) * 8;
    short8 v;
#pragma unroll
    for (int q = 0; q < 8; ++q) v[q] = f2bf(W2[(size_t)(k0 + q) * 512 + col]);
    for (int rp = 0; rp < nrep; ++rp)
      *(short8*)(WR + (size_t)rp * REP_SHORTS + (size_t)fid * 8) = v;
  } else if (blk < 132) {
    const int fid = (blk - 128) * 256 + tid;
    const int lane = fid & 63;
    const int ks = fid >> 6;
    const int ml = lane & 15;
    const int k0 = ks * 32 + (lane >> 4) * 8;
    short8 v;
#pragma unroll
    for (int q = 0; q < 8; ++q)
      v[q] = f2bf((ml < 5) ? W3[(size_t)(k0 + q) * 5 + ml] : 0.f);
    for (int rp = 0; rp < nrep; ++rp)
      *(short8*)(WR + (size_t)rp * REP_SHORTS + 262144 + (size_t)fid * 8) = v;
  } else {
    for (int idx = tid; idx < 512 * 16; idx += 256) {
      const int j = idx >> 4, c = idx & 15;
      W1T[idx] = (c < 15) ? W1[c * 512 + j] : 0.f;
    }
  }
}

// ---------------- persistent all-steps kernel ----------------
// 256 blocks (1/CU), 1024 threads (16 waves). Block = (b, 32-row chunk).
// u lives in LDS across steps; flux halo exchanged via relaxed agent-scope
// atomics + neighbor flag spin. W2/W3 read from this block's XCD-private
// replica; B2 k-sweep start rotated per (block, step) to defeat any
// streaming-bypass heuristic in TCC.
__global__ __launch_bounds__(1024, 4) void persist_kernel(
    const float* __restrict__ u0, const float* __restrict__ W1T,
    const float* __restrict__ b1, const short* __restrict__ WR,
    const float* __restrict__ b2, const float* __restrict__ b3, int nrep,
    float* __restrict__ states, float* __restrict__ actions,
    float* __restrict__ rewards, int* __restrict__ eflux,
    int* __restrict__ flags) {
  __shared__ float u_lds[VV][40];     // u at global n = n0-2+i
  __shared__ float flux_lds[VV][32];  // own flux for n0..n0+31
  __shared__ __align__(16) short h_lds[32 * 512];  // bf16, XOR-swizzled
  __shared__ float logits_lds[32][16];

  const int tid = threadIdx.x;
  const int blk = blockIdx.x;
  // XCD-affinity: whole 16-chunk ring of a given b on one XCD (speed only)
  const int xcd = blk & 7;
  const int sl = blk >> 3;
  const int b = 2 * xcd + (sl >> 4);
  const int c = sl & 15;
  const int n0 = c << 5;
  const int self = b * 16 + c;
  const int left = b * 16 + ((c + 15) & 15);
  const int right = b * 16 + ((c + 1) & 15);

  const int lane = tid & 63;
  const int wv = tid >> 6;
  const int ml = lane & 15;
  const int gg = lane >> 4;
  const int aswz = (ml & 7) << 3;

  // this block's XCD-private weight replica
  const short* Wrep = WR + (size_t)(xcd % nrep) * REP_SHORTS;
  const short8* B2p = (const short8*)Wrep;
  const short8* B3p = (const short8*)(Wrep + 262144);
  const int ct0 = wv * 2;

  if (tid < 108) {
    const int v = tid / 36;
    const int i = tid - v * 36;
    u_lds[v][i] = u0[(b * VV + v) * NN + ((n0 - 2 + i) & (NN - 1))];
  }
  __syncthreads();

  for (int t = 0; t <= TT; ++t) {
    if (t > 0) {
      // wait for neighbors' step-(t-1) flux
      if (tid == 0) {
        while (__hip_atomic_load(flags + left * 32, __ATOMIC_RELAXED,
                                 __HIP_MEMORY_SCOPE_AGENT) < t) {}
        while (__hip_atomic_load(flags + right * 32, __ATOMIC_RELAXED,
                                 __HIP_MEMORY_SCOPE_AGENT) < t) {}
      }
      __syncthreads();
      // A': u_t = u_{t-1} - 0.1*(flux - roll(flux,1)); write states[t-1]
      if (tid < 108) {
        const int v = tid / 36;
        const int i = tid - v * 36;  // u index, global n = n0-2+i
        const int ep = (t - 1) & 1;
        const int* lE = eflux + ((ep * 256 + left) * VV + v) * 8;
        const int* rE = eflux + ((ep * 256 + right) * VV + v) * 8;
        // F(j) = flux at global n0-3+j, j in [0,36]
        float Fa, Fb;
        if (i < 3)
          Fa = __int_as_float(__hip_atomic_load(lE + 2 + i, __ATOMIC_RELAXED,
                                                __HIP_MEMORY_SCOPE_AGENT));
        else if (i > 34)
          Fa = __int_as_float(__hip_atomic_load(rE + i - 35, __ATOMIC_RELAXED,
                                                __HIP_MEMORY_SCOPE_AGENT));
        else
          Fa = flux_lds[v][i - 3];
        if (i + 1 < 3)
          Fb = __int_as_float(__hip_atomic_load(lE + 3 + i, __ATOMIC_RELAXED,
                                                __HIP_MEMORY_SCOPE_AGENT));
        else if (i + 1 > 34)
          Fb = __int_as_float(__hip_atomic_load(rE + i - 34, __ATOMIC_RELAXED,
                                                __HIP_MEMORY_SCOPE_AGENT));
        else
          Fb = flux_lds[v][i - 2];
        const float un = u_lds[v][i] - DTDX * (Fb - Fa);
        u_lds[v][i] = un;
        if (i >= 2 && i < 34)
          states[(size_t)(t - 1) * BB * VV * NN + (b * VV + v) * NN +
                 (n0 - 2 + i)] = un;
      }
      __syncthreads();
    }
    if (t == TT) break;

    // ---- B1: h1 = tanh(feats @ W1 + b1), fp32 VALU ----
    {
      const int r = lane & 31;   // row, shared by 2 half-waves
      const int jh = lane >> 5;  // which 16-j half
      const int jbase = wv * 32 + jh * 16;
      float f[15];
#pragma unroll
      for (int v = 0; v < VV; ++v)
#pragma unroll
        for (int s = 0; s < SS; ++s) f[v * 5 + s] = u_lds[v][r + s];
      const int swz = (r & 7) << 3;
#pragma unroll
      for (int hf = 0; hf < 2; ++hf) {
        short8 hb;
#pragma unroll
        for (int q = 0; q < 8; ++q) {
          const int j = jbase + hf * 8 + q;
          const float4* wr = (const float4*)(W1T + j * 16);
          const float4 w0 = wr[0], w1 = wr[1], w2 = wr[2], w3 = wr[3];
          float a = b1[j];
          a += w0.x * f[0] + w0.y * f[1] + w0.z * f[2] + w0.w * f[3];
          a += w1.x * f[4] + w1.y * f[5] + w1.z * f[6] + w1.w * f[7];
          a += w2.x * f[8] + w2.y * f[9] + w2.z * f[10] + w2.w * f[11];
          a += w3.x * f[12] + w3.y * f[13] + w3.z * f[14];
          hb[q] = f2bf(fast_tanh(a));
        }
        const int ke = jbase + hf * 8;
        *(short8*)(&h_lds[r * 512 + (ke ^ swz)]) = hb;
      }
    }
    __syncthreads();

    // ---- B2: h2 = tanh(h1 @ W2 + b2), MFMA; rotated k-sweep ----
    f32x4 acc[2][2];
#pragma unroll
    for (int mt = 0; mt < 2; ++mt)
#pragma unroll
      for (int nt = 0; nt < 2; ++nt) acc[mt][nt] = (f32x4){0.f, 0.f, 0.f, 0.f};
    const int rot = ((blk >> 3) * 3 + t * 5) & 15;
#pragma unroll 4
    for (int kk = 0; kk < 16; ++kk) {
      const int ks = (kk + rot) & 15;
      const int k = ks * 32 + gg * 8;
      const short8 a0 = *(const short8*)(&h_lds[ml * 512 + (k ^ aswz)]);
      const short8 a1 = *(const short8*)(&h_lds[(16 + ml) * 512 + (k ^ aswz)]);
      const short8 b0 = B2p[(ct0 * 16 + ks) * 64 + lane];
      const short8 b1v = B2p[((ct0 + 1) * 16 + ks) * 64 + lane];
      acc[0][0] = __builtin_amdgcn_mfma_f32_16x16x32_bf16(a0, b0, acc[0][0], 0, 0, 0);
      acc[1][0] = __builtin_amdgcn_mfma_f32_16x16x32_bf16(a1, b0, acc[1][0], 0, 0, 0);
      acc[0][1] = __builtin_amdgcn_mfma_f32_16x16x32_bf16(a0, b1v, acc[0][1], 0, 0, 0);
      acc[1][1] = __builtin_amdgcn_mfma_f32_16x16x32_bf16(a1, b1v, acc[1][1], 0, 0, 0);
    }
    __syncthreads();  // all waves done reading h1

    // epilogue: h2 -> h_lds (C layout: row=gg*4+r, col=ml)
#pragma unroll
    for (int nt = 0; nt < 2; ++nt) {
      const int col = (ct0 + nt) * 16 + ml;
      const float bias = b2[col];
#pragma unroll
      for (int mt = 0; mt < 2; ++mt) {
#pragma unroll
        for (int r = 0; r < 4; ++r) {
          const int row = mt * 16 + gg * 4 + r;
          h_lds[row * 512 + (col ^ ((row & 7) << 3))] =
              f2bf(fast_tanh(acc[mt][nt][r] + bias));
        }
      }
    }
    __syncthreads();

    // ---- B3: logits = h2 @ W3 (waves 0,1) ----
    if (wv < 2) {
      f32x4 a3 = (f32x4){0.f, 0.f, 0.f, 0.f};
#pragma unroll 4
      for (int ks = 0; ks < 16; ++ks) {
        const int k = ks * 32 + gg * 8;
        const short8 a =
            *(const short8*)(&h_lds[(wv * 16 + ml) * 512 + (k ^ aswz)]);
        const short8 bb = B3p[ks * 64 + lane];
        a3 = __builtin_amdgcn_mfma_f32_16x16x32_bf16(a, bb, a3, 0, 0, 0);
      }
#pragma unroll
      for (int r = 0; r < 4; ++r) logits_lds[wv * 16 + gg * 4 + r][ml] = a3[r];
    }
    __syncthreads();

    // ---- B4: softmax, reward, actions, flux (+ halo publish) ----
    if (tid < 32) {
      const int r = tid;
      const int n = n0 + r;
      float lg[5];
#pragma unroll
      for (int s = 0; s < 5; ++s) lg[s] = logits_lds[r][s] + b3[s];
      const float m =
          fmaxf(fmaxf(fmaxf(lg[0], lg[1]), fmaxf(lg[2], lg[3])), lg[4]);
      float e[5], sum = 0.f;
#pragma unroll
      for (int s = 0; s < 5; ++s) {
        e[s] = __expf(lg[s] - m);
        sum += e[s];
      }
      const float inv = 1.f / sum;
      float w[5], rw = 0.f;
#pragma unroll
      for (int s = 0; s < 5; ++s) {
        w[s] = e[s] * inv;
        rw += w[s] * w[s];
      }
      float* ap = actions + (size_t)t * BB * NN * SS + ((size_t)b * NN + n) * SS;
#pragma unroll
      for (int s = 0; s < 5; ++s) ap[s] = w[s];
      rewards[(size_t)t * BB * NN + b * NN + n] = -rw;
      const int p = t & 1;
#pragma unroll
      for (int v = 0; v < VV; ++v) {
        float fx = 0.f;
#pragma unroll
        for (int s = 0; s < 5; ++s) fx += u_lds[v][r + s] * w[s];
        flux_lds[v][r] = fx;
        int* sE = eflux + ((p * 256 + self) * VV + v) * 8;
        if (r < 2)
          __hip_atomic_store(sE + r, __float_as_int(fx), __ATOMIC_RELAXED,
                             __HIP_MEMORY_SCOPE_AGENT);
        if (r >= 29)
          __hip_atomic_store(sE + 2 + (r - 29), __float_as_int(fx),
                             __ATOMIC_RELAXED, __HIP_MEMORY_SCOPE_AGENT);
      }
    }
    __syncthreads();  // drains vmcnt: halo atomics complete before flag
    if (tid == 0)
      __hip_atomic_store(flags + self * 32, t + 1, __ATOMIC_RELAXED,
                         __HIP_MEMORY_SCOPE_AGENT);
  }
}

extern "C" void kernel_launch(void* const* d_in, const int* in_sizes, int n_in,
                              void* d_out, int out_size, void* d_ws,
                              size_t ws_size, hipStream_t stream) {
  const float* u0 = (const float*)d_in[0];
  const float* W1 = (const float*)d_in[1];
  const float* b1 = (const float*)d_in[2];
  const float* W2 = (const float*)d_in[3];
  const float* b2 = (const float*)d_in[4];
  const float* W3 = (const float*)d_in[5];
  const float* b3 = (const float*)d_in[6];

  float* states = (float*)d_out;                         // [32,16,3,512]
  float* actions = states + (size_t)TT * BB * VV * NN;   // [32,16,512,5]
  float* rewards = actions + (size_t)TT * BB * NN * SS;  // [32,16,512]

  char* ws = (char*)d_ws;
  float* W1T = (float*)ws;                    // 32 KB
  int* eflux = (int*)(ws + 32768);            // 48 KB
  int* flags = (int*)(ws + 32768 + 49152);    // 32 KB
  short* WR = (short*)(ws + WS_FIXED);        // replicas

  int nrep = 1;
  if (ws_size > (size_t)WS_FIXED)
    nrep = (int)((ws_size - WS_FIXED) / REP_BYTES);
  if (nrep < 1) nrep = 1;
  if (nrep > 8) nrep = 8;

  hipMemsetAsync(flags, 0, 256 * 32 * sizeof(int), stream);
  init_repack<<<dim3(133), dim3(256), 0, stream>>>(W1, W2, W3, W1T, WR, nrep);

  persist_kernel<<<dim3(256), dim3(1024), 0, stream>>>(
      u0, W1T, b1, WR, b2, b3, nrep, states, actions, rewards, eflux, flags);
}

// Round 7
// 649.979 us; speedup vs baseline: 2.9276x; 2.3424x over previous
//
#include <hip/hip_runtime.h>
#include <hip/hip_bf16.h>

typedef __attribute__((ext_vector_type(8))) short short8;
typedef __attribute__((ext_vector_type(4))) float f32x4;

#define BB 16
#define VV 3
#define NN 512
#define SS 5
#define TT 32
#define DTDX 0.1f

#define GLOAD_LDS16(g, l)                                          \
  __builtin_amdgcn_global_load_lds(                                \
      (const __attribute__((address_space(1))) void*)(g),          \
      (__attribute__((address_space(3))) void*)(l), 16, 0, 0)

__device__ __forceinline__ float fast_tanh(float x) {
  float xc = fminf(fmaxf(x, -9.f), 9.f);
  float e = __expf(2.f * xc);
  return (e - 1.f) * __builtin_amdgcn_rcpf(e + 1.f);
}

__device__ __forceinline__ short f2bf(float x) {
  __hip_bfloat16 h = __float2bfloat16(x);
  return __builtin_bit_cast(short, h);
}

// ---------------- init: weight repack ----------------
// W1T[j][c] fp32 [512][16] (c=15 zero-padded)
// W2F: fragment-ordered bf16: frag(ct,ks,lane) at ((ct*16+ks)*64+lane)*8
// W3F: fragment-ordered bf16 for W3 (cols>=5 zero): frag(ks,lane)
__global__ void init_repack(const float* __restrict__ W1,
                            const float* __restrict__ W2,
                            const float* __restrict__ W3,
                            float* __restrict__ W1T,
                            short* __restrict__ W2F,
                            short* __restrict__ W3F) {
  const int blk = blockIdx.x;
  const int tid = threadIdx.x;
  if (blk < 128) {
    const int fid = blk * 256 + tid;
    const int lane = fid & 63;
    const int rest = fid >> 6;
    const int ks = rest & 15;
    const int ct = rest >> 4;
    const int col = ct * 16 + (lane & 15);
    const int k0 = ks * 32 + (lane >> 4) * 8;
    short8 v;
#pragma unroll
    for (int q = 0; q < 8; ++q) v[q] = f2bf(W2[(size_t)(k0 + q) * 512 + col]);
    *(short8*)(W2F + (size_t)fid * 8) = v;
  } else if (blk < 132) {
    const int fid = (blk - 128) * 256 + tid;
    const int lane = fid & 63;
    const int ks = fid >> 6;
    const int ml = lane & 15;
    const int k0 = ks * 32 + (lane >> 4) * 8;
    short8 v;
#pragma unroll
    for (int q = 0; q < 8; ++q)
      v[q] = f2bf((ml < 5) ? W3[(size_t)(k0 + q) * 5 + ml] : 0.f);
    *(short8*)(W3F + (size_t)fid * 8) = v;
  } else {
    for (int idx = tid; idx < 512 * 16; idx += 256) {
      const int j = idx >> 4, c = idx & 15;
      W1T[idx] = (c < 15) ? W1[c * 512 + j] : 0.f;
    }
  }
}

// ---------------- per-step fused cell ----------------
// Block = (batch b, 32-row chunk n0), 1024 threads = 16 waves.
// B2's W2 fragments staged via global_load_lds into a per-wave 3-slot LDS
// ring with counted vmcnt waits (never drain mid-loop): attacks the ~12
// GB/s/CU MSHR-limited streaming wall of the load->MFMA-coupled loop.
template <bool FIRST>
__global__ __launch_bounds__(1024, 4) void step_kernel(
    const float* __restrict__ u_prev, const float* __restrict__ flux_prev,
    const float* __restrict__ W1T, const float* __restrict__ b1,
    const short* __restrict__ W2F, const float* __restrict__ b2,
    const short* __restrict__ W3F, const float* __restrict__ b3,
    float* __restrict__ u_out, float* __restrict__ states_out,
    float* __restrict__ flux_out, float* __restrict__ actions_out,
    float* __restrict__ rewards_out) {
  __shared__ float u_lds[VV][40];
  __shared__ __align__(16) short h_lds[32 * 512];      // bf16, XOR-swizzled
  __shared__ __align__(16) short ring[16 * 3 * 1024];  // per-wave B ring, 96KB
  __shared__ float logits_lds[32][16];

  const int tid = threadIdx.x;
  const int blk = blockIdx.x;
  const int b = blk >> 4;
  const int n0 = (blk & 15) << 5;

  // ---- Phase A: state update / load ----
  if (tid < 108) {
    const int v = tid / 36;
    const int i = tid - v * 36;
    const int n = (n0 - 2 + i) & (NN - 1);
    const int base = (b * VV + v) * NN;
    const int gi = base + n;
    float uv;
    if (FIRST) {
      uv = u_prev[gi];
    } else {
      const int nm = (n - 1) & (NN - 1);
      uv = u_prev[gi] - DTDX * (flux_prev[base + n] - flux_prev[base + nm]);
      if (i >= 2 && i < 34) {
        u_out[gi] = uv;
        states_out[gi] = uv;
      }
    }
    u_lds[v][i] = uv;
  }
  __syncthreads();

  const int lane = tid & 63;
  const int wv = tid >> 6;

  // ---- Phase B1: h1 = tanh(feats @ W1 + b1), fp32 VALU ----
  {
    const int r = lane & 31;   // row 0..31 (shared by 2 half-waves)
    const int jh = lane >> 5;  // which 16-j half
    const int jbase = wv * 32 + jh * 16;
    float f[15];
#pragma unroll
    for (int v = 0; v < VV; ++v)
#pragma unroll
      for (int s = 0; s < SS; ++s) f[v * 5 + s] = u_lds[v][r + s];
    const int swz = (r & 15) << 3;
#pragma unroll
    for (int hf = 0; hf < 2; ++hf) {
      short8 hb;
#pragma unroll
      for (int q = 0; q < 8; ++q) {
        const int j = jbase + hf * 8 + q;
        const float4* wr = (const float4*)(W1T + j * 16);
        const float4 w0 = wr[0], w1 = wr[1], w2 = wr[2], w3 = wr[3];
        float a = b1[j];
        a += w0.x * f[0] + w0.y * f[1] + w0.z * f[2] + w0.w * f[3];
        a += w1.x * f[4] + w1.y * f[5] + w1.z * f[6] + w1.w * f[7];
        a += w2.x * f[8] + w2.y * f[9] + w2.z * f[10] + w2.w * f[11];
        a += w3.x * f[12] + w3.y * f[13] + w3.z * f[14];
        hb[q] = f2bf(fast_tanh(a));
      }
      const int ke = jbase + hf * 8;
      *(short8*)(&h_lds[r * 512 + (ke ^ swz)]) = hb;
    }
  }
  __syncthreads();  // drains vmcnt to 0: ring waits below are exact

  const int ml = lane & 15;
  const int gg = lane >> 4;
  const int aswz = ml << 3;
  const int ct0 = wv * 2;
  short* const rb = ring + wv * 3072;

  // ---- Phase B2: h2 = tanh(h1 @ W2 + b2); B staged via global_load_lds ----
  f32x4 acc[2][2];
#pragma unroll
  for (int mt = 0; mt < 2; ++mt)
#pragma unroll
    for (int nt = 0; nt < 2; ++nt) acc[mt][nt] = (f32x4){0.f, 0.f, 0.f, 0.f};

#define ISSUE_SLOT(ks2)                                                       \
  do {                                                                        \
    const int _s = (ks2) % 3;                                                 \
    GLOAD_LDS16(W2F + ((size_t)(ct0 * 16 + (ks2)) * 64 + lane) * 8,           \
                rb + _s * 1024);                                              \
    GLOAD_LDS16(W2F + ((size_t)((ct0 + 1) * 16 + (ks2)) * 64 + lane) * 8,     \
                rb + _s * 1024 + 512);                                        \
  } while (0)

  ISSUE_SLOT(0);
  ISSUE_SLOT(1);
#pragma unroll
  for (int ks = 0; ks < 16; ++ks) {
    if (ks < 14) {
      ISSUE_SLOT(ks + 2);
      asm volatile("s_waitcnt vmcnt(4)" ::: "memory");
    } else if (ks == 14) {
      asm volatile("s_waitcnt vmcnt(2)" ::: "memory");
    } else {
      asm volatile("s_waitcnt vmcnt(0)" ::: "memory");
    }
    const int slot = ks % 3;
    const int k = ks * 32 + gg * 8;
    const short8 a0 = *(const short8*)(&h_lds[ml * 512 + (k ^ aswz)]);
    const short8 a1 = *(const short8*)(&h_lds[(16 + ml) * 512 + (k ^ aswz)]);
    const short8 b0 = *(const short8*)(rb + slot * 1024 + lane * 8);
    const short8 b1v = *(const short8*)(rb + slot * 1024 + 512 + lane * 8);
    acc[0][0] = __builtin_amdgcn_mfma_f32_16x16x32_bf16(a0, b0, acc[0][0], 0, 0, 0);
    acc[1][0] = __builtin_amdgcn_mfma_f32_16x16x32_bf16(a1, b0, acc[1][0], 0, 0, 0);
    acc[0][1] = __builtin_amdgcn_mfma_f32_16x16x32_bf16(a0, b1v, acc[0][1], 0, 0, 0);
    acc[1][1] = __builtin_amdgcn_mfma_f32_16x16x32_bf16(a1, b1v, acc[1][1], 0, 0, 0);
  }
#undef ISSUE_SLOT
  __syncthreads();  // all waves done reading h1

  // epilogue: h2 -> h_lds (C layout: row=gg*4+r, col=ml)
#pragma unroll
  for (int nt = 0; nt < 2; ++nt) {
    const int col = (ct0 + nt) * 16 + ml;
    const float bias = b2[col];
#pragma unroll
    for (int mt = 0; mt < 2; ++mt) {
#pragma unroll
      for (int r = 0; r < 4; ++r) {
        const int row = mt * 16 + gg * 4 + r;
        h_lds[row * 512 + (col ^ ((row & 15) << 3))] =
            f2bf(fast_tanh(acc[mt][nt][r] + bias));
      }
    }
  }
  __syncthreads();

  // ---- Phase B3: logits = h2 @ W3 + b3 (waves 0,1) ----
  if (wv < 2) {
    f32x4 a3 = (f32x4){0.f, 0.f, 0.f, 0.f};
    const short8* B3p = (const short8*)W3F;
#pragma unroll 4
    for (int ks = 0; ks < 16; ++ks) {
      const int k = ks * 32 + gg * 8;
      const short8 a =
          *(const short8*)(&h_lds[(wv * 16 + ml) * 512 + (k ^ aswz)]);
      const short8 bb = B3p[ks * 64 + lane];
      a3 = __builtin_amdgcn_mfma_f32_16x16x32_bf16(a, bb, a3, 0, 0, 0);
    }
#pragma unroll
    for (int r = 0; r < 4; ++r) logits_lds[wv * 16 + gg * 4 + r][ml] = a3[r];
  }
  __syncthreads();

  // ---- Phase B4: softmax, reward, flux, outputs ----
  if (tid < 32) {
    const int r = tid;
    const int n = n0 + r;
    float lg[5];
#pragma unroll
    for (int s = 0; s < 5; ++s) lg[s] = logits_lds[r][s] + b3[s];
    const float m =
        fmaxf(fmaxf(fmaxf(lg[0], lg[1]), fmaxf(lg[2], lg[3])), lg[4]);
    float e[5], sum = 0.f;
#pragma unroll
    for (int s = 0; s < 5; ++s) {
      e[s] = __expf(lg[s] - m);
      sum += e[s];
    }
    const float inv = 1.f / sum;
    float w[5], rw = 0.f;
#pragma unroll
    for (int s = 0; s < 5; ++s) {
      w[s] = e[s] * inv;
      rw += w[s] * w[s];
    }
    float* ap = actions_out + ((size_t)b * NN + n) * SS;
#pragma unroll
    for (int s = 0; s < 5; ++s) ap[s] = w[s];
    rewards_out[b * NN + n] = -rw;
#pragma unroll
    for (int v = 0; v < VV; ++v) {
      float fx = 0.f;
#pragma unroll
      for (int s = 0; s < 5; ++s) fx += u_lds[v][r + s] * w[s];
      flux_out[(b * VV + v) * NN + n] = fx;
    }
  }
}

// ---------------- epilogue: u_32 -> states[31] ----------------
__global__ void final_update(const float* __restrict__ u_prev,
                             const float* __restrict__ flux_prev,
                             float* __restrict__ states_out) {
  const int idx = blockIdx.x * 256 + threadIdx.x;
  if (idx < BB * VV * NN) {
    const int n = idx & (NN - 1);
    const int base = idx - n;
    const int nm = (n - 1) & (NN - 1);
    states_out[idx] =
        u_prev[idx] - DTDX * (flux_prev[idx] - flux_prev[base + nm]);
  }
}

extern "C" void kernel_launch(void* const* d_in, const int* in_sizes, int n_in,
                              void* d_out, int out_size, void* d_ws,
                              size_t ws_size, hipStream_t stream) {
  const float* u0 = (const float*)d_in[0];
  const float* W1 = (const float*)d_in[1];
  const float* b1 = (const float*)d_in[2];
  const float* W2 = (const float*)d_in[3];
  const float* b2 = (const float*)d_in[4];
  const float* W3 = (const float*)d_in[5];
  const float* b3 = (const float*)d_in[6];

  float* states = (float*)d_out;                         // [32,16,3,512]
  float* actions = states + (size_t)TT * BB * VV * NN;   // [32,16,512,5]
  float* rewards = actions + (size_t)TT * BB * NN * SS;  // [32,16,512]

  char* ws = (char*)d_ws;
  float* ubuf[2] = {(float*)ws, (float*)(ws + 98304)};
  float* fbuf[2] = {(float*)(ws + 2 * 98304), (float*)(ws + 3 * 98304)};
  float* W1T = (float*)(ws + 4 * 98304);
  short* W2F = (short*)(ws + 4 * 98304 + 32768);
  short* W3F = (short*)(ws + 4 * 98304 + 32768 + 524288);

  init_repack<<<dim3(133), dim3(256), 0, stream>>>(W1, W2, W3, W1T, W2F, W3F);

  for (int t = 0; t < TT; ++t) {
    if (t == 0) {
      step_kernel<true><<<dim3(256), dim3(1024), 0, stream>>>(
          u0, (const float*)nullptr, W1T, b1, W2F, b2, W3F, b3,
          (float*)nullptr, (float*)nullptr, fbuf[0], actions, rewards);
    } else {
      const float* up = (t == 1) ? u0 : ubuf[(t - 1) & 1];
      step_kernel<false><<<dim3(256), dim3(1024), 0, stream>>>(
          up, fbuf[(t - 1) & 1], W1T, b1, W2F, b2, W3F, b3, ubuf[t & 1],
          states + (size_t)(t - 1) * BB * VV * NN, fbuf[t & 1],
          actions + (size_t)t * BB * NN * SS, rewards + (size_t)t * BB * NN);
    }
  }
  final_update<<<dim3((BB * VV * NN + 255) / 256), dim3(256), 0, stream>>>(
      ubuf[1], fbuf[1], states + (size_t)(TT - 1) * BB * VV * NN);
}

// Round 8
// 376.937 us; speedup vs baseline: 5.0483x; 1.7244x over previous
//
#include <hip/hip_runtime.h>
#include <hip/hip_bf16.h>

typedef __attribute__((ext_vector_type(8))) short short8;
typedef __attribute__((ext_vector_type(4))) float f32x4;

#define BB 16
#define VV 3
#define NN 512
#define SS 5
#define TT 32
#define DTDX 0.1f

#define GLOAD_LDS16(g, l)                                          \
  __builtin_amdgcn_global_load_lds(                                \
      (const __attribute__((address_space(1))) void*)(g),          \
      (__attribute__((address_space(3))) void*)(l), 16, 0, 0)

__device__ __forceinline__ float fast_tanh(float x) {
  float xc = fminf(fmaxf(x, -9.f), 9.f);
  float e = __expf(2.f * xc);
  return (e - 1.f) * __builtin_amdgcn_rcpf(e + 1.f);
}

__device__ __forceinline__ short f2bf(float x) {
  __hip_bfloat16 h = __float2bfloat16(x);
  return __builtin_bit_cast(short, h);
}

// ---------------- init: weight repack ----------------
// All weights in the verified 16x16x32 fragment format:
//   frag(nt, ks, lane): col = nt*16 + (lane&15), k = ks*32 + (lane>>4)*8 + q
// W2F: [32 nt][16 ks] frags (512 KB)
// W3F: [1 nt][16 ks] frags, cols>=5 zero (16 KB)
// W1F: [32 nt][1 ks] frags (32 KB); k<15 -> W1[k][col], k==15 -> b1[col]
//      (bias folded: A-operand supplies 1.0 at k=15), k>15 -> 0
__global__ void init_repack(const float* __restrict__ W1,
                            const float* __restrict__ b1,
                            const float* __restrict__ W2,
                            const float* __restrict__ W3,
                            short* __restrict__ W1F,
                            short* __restrict__ W2F,
                            short* __restrict__ W3F) {
  const int blk = blockIdx.x;
  const int tid = threadIdx.x;
  if (blk < 128) {
    const int fid = blk * 256 + tid;
    const int lane = fid & 63;
    const int rest = fid >> 6;
    const int ks = rest & 15;
    const int ct = rest >> 4;
    const int col = ct * 16 + (lane & 15);
    const int k0 = ks * 32 + (lane >> 4) * 8;
    short8 v;
#pragma unroll
    for (int q = 0; q < 8; ++q) v[q] = f2bf(W2[(size_t)(k0 + q) * 512 + col]);
    *(short8*)(W2F + (size_t)fid * 8) = v;
  } else if (blk < 132) {
    const int fid = (blk - 128) * 256 + tid;
    const int lane = fid & 63;
    const int ks = fid >> 6;
    const int ml = lane & 15;
    const int k0 = ks * 32 + (lane >> 4) * 8;
    short8 v;
#pragma unroll
    for (int q = 0; q < 8; ++q)
      v[q] = f2bf((ml < 5) ? W3[(size_t)(k0 + q) * 5 + ml] : 0.f);
    *(short8*)(W3F + (size_t)fid * 8) = v;
  } else {
    // W1F: 2048 fragments
    for (int fid = tid; fid < 2048; fid += 256) {
      const int lane = fid & 63;
      const int nt = fid >> 6;
      const int col = nt * 16 + (lane & 15);
      const int k0 = (lane >> 4) * 8;
      short8 v;
#pragma unroll
      for (int q = 0; q < 8; ++q) {
        const int k = k0 + q;
        float x = 0.f;
        if (k < 15) x = W1[(size_t)k * 512 + col];
        else if (k == 15) x = b1[col];
        v[q] = f2bf(x);
      }
      *(short8*)(W1F + (size_t)fid * 8) = v;
    }
  }
}

// ---------------- per-step fused cell ----------------
// Block = (batch b, 32-row chunk n0), 1024 threads = 16 waves.
// B2's W2 fragments staged via global_load_lds into a per-wave 3-slot LDS
// ring with counted vmcnt waits; slots 0-1 issued before Phase A so the
// pipeline fill hides under the A/B1 latency (A's barrier drains vmcnt,
// making the in-loop counted waits exact). GEMM1 is MFMA (bias folded).
template <bool FIRST>
__global__ __launch_bounds__(1024, 4) void step_kernel(
    const float* __restrict__ u_prev, const float* __restrict__ flux_prev,
    const short* __restrict__ W1F, const short* __restrict__ W2F,
    const float* __restrict__ b2, const short* __restrict__ W3F,
    const float* __restrict__ b3, float* __restrict__ u_out,
    float* __restrict__ states_out, float* __restrict__ flux_out,
    float* __restrict__ actions_out, float* __restrict__ rewards_out) {
  __shared__ float u_lds[VV][40];
  __shared__ __align__(16) short h_lds[32 * 512];      // bf16, XOR-swizzled
  __shared__ __align__(16) short ring[16 * 3 * 1024];  // per-wave B ring, 96KB
  __shared__ float logits_lds[32][16];

  const int tid = threadIdx.x;
  const int blk = blockIdx.x;
  const int b = blk >> 4;
  const int n0 = (blk & 15) << 5;

  const int lane = tid & 63;
  const int wv = tid >> 6;
  const int ml = lane & 15;
  const int gg = lane >> 4;
  const int aswz = ml << 3;
  const int ct0 = wv * 2;
  short* const rb = ring + wv * 3072;

#define ISSUE_SLOT(ks2)                                                       \
  do {                                                                        \
    const int _s = (ks2) % 3;                                                 \
    GLOAD_LDS16(W2F + ((size_t)(ct0 * 16 + (ks2)) * 64 + lane) * 8,           \
                rb + _s * 1024);                                              \
    GLOAD_LDS16(W2F + ((size_t)((ct0 + 1) * 16 + (ks2)) * 64 + lane) * 8,     \
                rb + _s * 1024 + 512);                                        \
  } while (0)

  // prefetch first two ring slots; they complete during Phase A + B1
  ISSUE_SLOT(0);
  ISSUE_SLOT(1);

  // ---- Phase A: state update / load ----
  if (tid < 108) {
    const int v = tid / 36;
    const int i = tid - v * 36;
    const int n = (n0 - 2 + i) & (NN - 1);
    const int base = (b * VV + v) * NN;
    const int gi = base + n;
    float uv;
    if (FIRST) {
      uv = u_prev[gi];
    } else {
      const int nm = (n - 1) & (NN - 1);
      uv = u_prev[gi] - DTDX * (flux_prev[base + n] - flux_prev[base + nm]);
      if (i >= 2 && i < 34) {
        u_out[gi] = uv;
        states_out[gi] = uv;
      }
    }
    u_lds[v][i] = uv;
  }
  __syncthreads();  // drains vmcnt(0): prefetched slots resident

  // ---- B1: h1 = tanh(feats @ W1) via MFMA; K=32 (k=15 carries bias) ----
  {
    const short8 wb0 = *(const short8*)(W1F + ((size_t)ct0 * 64 + lane) * 8);
    const short8 wb1 =
        *(const short8*)(W1F + ((size_t)(ct0 + 1) * 64 + lane) * 8);
    short8 afr[2];
#pragma unroll
    for (int mt = 0; mt < 2; ++mt) {
      const int r = mt * 16 + ml;
      short8 a;
#pragma unroll
      for (int q = 0; q < 8; ++q) a[q] = 0;
      if (gg == 0) {
#pragma unroll
        for (int q = 0; q < 8; ++q) {  // k = 0..7
          const int v = q / 5, s = q % 5;
          a[q] = f2bf(u_lds[v][r + s]);
        }
      } else if (gg == 1) {
#pragma unroll
        for (int q = 0; q < 7; ++q) {  // k = 8..14
          const int k = 8 + q;
          const int v = k / 5, s = k % 5;
          a[q] = f2bf(u_lds[v][r + s]);
        }
        a[7] = f2bf(1.0f);  // bias row (k=15)
      }
      afr[mt] = a;
    }
    f32x4 c[2][2];
#pragma unroll
    for (int mt = 0; mt < 2; ++mt)
#pragma unroll
      for (int nt = 0; nt < 2; ++nt) c[mt][nt] = (f32x4){0.f, 0.f, 0.f, 0.f};
    c[0][0] = __builtin_amdgcn_mfma_f32_16x16x32_bf16(afr[0], wb0, c[0][0], 0, 0, 0);
    c[1][0] = __builtin_amdgcn_mfma_f32_16x16x32_bf16(afr[1], wb0, c[1][0], 0, 0, 0);
    c[0][1] = __builtin_amdgcn_mfma_f32_16x16x32_bf16(afr[0], wb1, c[0][1], 0, 0, 0);
    c[1][1] = __builtin_amdgcn_mfma_f32_16x16x32_bf16(afr[1], wb1, c[1][1], 0, 0, 0);
#pragma unroll
    for (int nt = 0; nt < 2; ++nt) {
      const int col = (ct0 + nt) * 16 + ml;
#pragma unroll
      for (int mt = 0; mt < 2; ++mt) {
#pragma unroll
        for (int r = 0; r < 4; ++r) {
          const int row = mt * 16 + gg * 4 + r;
          h_lds[row * 512 + (col ^ ((row & 15) << 3))] =
              f2bf(fast_tanh(c[mt][nt][r]));
        }
      }
    }
  }
  __syncthreads();

  // ---- Phase B2: h2 = tanh(h1 @ W2 + b2); B staged via global_load_lds ----
  f32x4 acc[2][2];
#pragma unroll
  for (int mt = 0; mt < 2; ++mt)
#pragma unroll
    for (int nt = 0; nt < 2; ++nt) acc[mt][nt] = (f32x4){0.f, 0.f, 0.f, 0.f};

#pragma unroll
  for (int ks = 0; ks < 16; ++ks) {
    if (ks < 14) {
      ISSUE_SLOT(ks + 2);
      asm volatile("s_waitcnt vmcnt(4)" ::: "memory");
    } else if (ks == 14) {
      asm volatile("s_waitcnt vmcnt(2)" ::: "memory");
    } else {
      asm volatile("s_waitcnt vmcnt(0)" ::: "memory");
    }
    const int slot = ks % 3;
    const int k = ks * 32 + gg * 8;
    const short8 a0 = *(const short8*)(&h_lds[ml * 512 + (k ^ aswz)]);
    const short8 a1 = *(const short8*)(&h_lds[(16 + ml) * 512 + (k ^ aswz)]);
    const short8 b0 = *(const short8*)(rb + slot * 1024 + lane * 8);
    const short8 b1v = *(const short8*)(rb + slot * 1024 + 512 + lane * 8);
    __builtin_amdgcn_s_setprio(1);
    acc[0][0] = __builtin_amdgcn_mfma_f32_16x16x32_bf16(a0, b0, acc[0][0], 0, 0, 0);
    acc[1][0] = __builtin_amdgcn_mfma_f32_16x16x32_bf16(a1, b0, acc[1][0], 0, 0, 0);
    acc[0][1] = __builtin_amdgcn_mfma_f32_16x16x32_bf16(a0, b1v, acc[0][1], 0, 0, 0);
    acc[1][1] = __builtin_amdgcn_mfma_f32_16x16x32_bf16(a1, b1v, acc[1][1], 0, 0, 0);
    __builtin_amdgcn_s_setprio(0);
  }
#undef ISSUE_SLOT
  __syncthreads();  // all waves done reading h1

  // epilogue: h2 -> h_lds (C layout: row=gg*4+r, col=ml)
#pragma unroll
  for (int nt = 0; nt < 2; ++nt) {
    const int col = (ct0 + nt) * 16 + ml;
    const float bias = b2[col];
#pragma unroll
    for (int mt = 0; mt < 2; ++mt) {
#pragma unroll
      for (int r = 0; r < 4; ++r) {
        const int row = mt * 16 + gg * 4 + r;
        h_lds[row * 512 + (col ^ ((row & 15) << 3))] =
            f2bf(fast_tanh(acc[mt][nt][r] + bias));
      }
    }
  }
  __syncthreads();

  // ---- Phase B3: logits = h2 @ W3 + b3 (waves 0,1) ----
  if (wv < 2) {
    f32x4 a3 = (f32x4){0.f, 0.f, 0.f, 0.f};
    const short8* B3p = (const short8*)W3F;
#pragma unroll 4
    for (int ks = 0; ks < 16; ++ks) {
      const int k = ks * 32 + gg * 8;
      const short8 a =
          *(const short8*)(&h_lds[(wv * 16 + ml) * 512 + (k ^ aswz)]);
      const short8 bb = B3p[ks * 64 + lane];
      a3 = __builtin_amdgcn_mfma_f32_16x16x32_bf16(a, bb, a3, 0, 0, 0);
    }
#pragma unroll
    for (int r = 0; r < 4; ++r) logits_lds[wv * 16 + gg * 4 + r][ml] = a3[r];
  }
  __syncthreads();

  // ---- Phase B4: softmax, reward, flux, outputs ----
  if (tid < 32) {
    const int r = tid;
    const int n = n0 + r;
    float lg[5];
#pragma unroll
    for (int s = 0; s < 5; ++s) lg[s] = logits_lds[r][s] + b3[s];
    const float m =
        fmaxf(fmaxf(fmaxf(lg[0], lg[1]), fmaxf(lg[2], lg[3])), lg[4]);
    float e[5], sum = 0.f;
#pragma unroll
    for (int s = 0; s < 5; ++s) {
      e[s] = __expf(lg[s] - m);
      sum += e[s];
    }
    const float inv = 1.f / sum;
    float w[5], rw = 0.f;
#pragma unroll
    for (int s = 0; s < 5; ++s) {
      w[s] = e[s] * inv;
      rw += w[s] * w[s];
    }
    float* ap = actions_out + ((size_t)b * NN + n) * SS;
#pragma unroll
    for (int s = 0; s < 5; ++s) ap[s] = w[s];
    rewards_out[b * NN + n] = -rw;
#pragma unroll
    for (int v = 0; v < VV; ++v) {
      float fx = 0.f;
#pragma unroll
      for (int s = 0; s < 5; ++s) fx += u_lds[v][r + s] * w[s];
      flux_out[(b * VV + v) * NN + n] = fx;
    }
  }
}

// ---------------- epilogue: u_32 -> states[31] ----------------
__global__ void final_update(const float* __restrict__ u_prev,
                             const float* __restrict__ flux_prev,
                             float* __restrict__ states_out) {
  const int idx = blockIdx.x * 256 + threadIdx.x;
  if (idx < BB * VV * NN) {
    const int n = idx & (NN - 1);
    const int base = idx - n;
    const int nm = (n - 1) & (NN - 1);
    states_out[idx] =
        u_prev[idx] - DTDX * (flux_prev[idx] - flux_prev[base + nm]);
  }
}

extern "C" void kernel_launch(void* const* d_in, const int* in_sizes, int n_in,
                              void* d_out, int out_size, void* d_ws,
                              size_t ws_size, hipStream_t stream) {
  const float* u0 = (const float*)d_in[0];
  const float* W1 = (const float*)d_in[1];
  const float* b1 = (const float*)d_in[2];
  const float* W2 = (const float*)d_in[3];
  const float* b2 = (const float*)d_in[4];
  const float* W3 = (const float*)d_in[5];
  const float* b3 = (const float*)d_in[6];

  float* states = (float*)d_out;                         // [32,16,3,512]
  float* actions = states + (size_t)TT * BB * VV * NN;   // [32,16,512,5]
  float* rewards = actions + (size_t)TT * BB * NN * SS;  // [32,16,512]

  char* ws = (char*)d_ws;
  float* ubuf[2] = {(float*)ws, (float*)(ws + 98304)};
  float* fbuf[2] = {(float*)(ws + 2 * 98304), (float*)(ws + 3 * 98304)};
  short* W1F = (short*)(ws + 4 * 98304);                    // 32 KB
  short* W2F = (short*)(ws + 4 * 98304 + 32768);            // 512 KB
  short* W3F = (short*)(ws + 4 * 98304 + 32768 + 524288);   // 16 KB

  init_repack<<<dim3(133), dim3(256), 0, stream>>>(W1, b1, W2, W3, W1F, W2F,
                                                   W3F);

  for (int t = 0; t < TT; ++t) {
    if (t == 0) {
      step_kernel<true><<<dim3(256), dim3(1024), 0, stream>>>(
          u0, (const float*)nullptr, W1F, W2F, b2, W3F, b3, (float*)nullptr,
          (float*)nullptr, fbuf[0], actions, rewards);
    } else {
      const float* up = (t == 1) ? u0 : ubuf[(t - 1) & 1];
      step_kernel<false><<<dim3(256), dim3(1024), 0, stream>>>(
          up, fbuf[(t - 1) & 1], W1F, W2F, b2, W3F, b3, ubuf[t & 1],
          states + (size_t)(t - 1) * BB * VV * NN, fbuf[t & 1],
          actions + (size_t)t * BB * NN * SS, rewards + (size_t)t * BB * NN);
    }
  }
  final_update<<<dim3((BB * VV * NN + 255) / 256), dim3(256), 0, stream>>>(
      ubuf[1], fbuf[1], states + (size_t)(TT - 1) * BB * VV * NN);
}